// Round 2
// baseline (69.761 us; speedup 1.0000x reference)
//
#include <hip/hip_runtime.h>

#define B_DIM   1024
#define IN_DIM  1024
#define OUT_DIM 2048
#define NBITS   6
#define NENT    64   // 1 << NBITS

#define OB   256     // o per block (== blockDim.x)
#define BB   16      // b per block
#define LROW 65      // padded lut row stride in words -> conflict-free row pull
// LDS words needed: max(OB*LROW, BB*IN_DIM) = max(16640, 16384) = 16640 (65 KiB)

// R(next): same schedule as the 69.6us kernel, but the Horner fold is
// restructured to fold bit 5 LAST: two independent 32-coeff half-folds
// (peak 16 live temps each) + one combining FMA, and the b-loop unroll is
// reduced 4 -> 2. Theory: the old w[32] x unroll-4 + v[64] structure sat at
// the 256-VGPR launch_bounds cap and spilled v/w to scratch (~0.5 GB HBM
// scratch traffic == the observed ~70us floor). This variant's worst-case
// peak pressure is ~130-150 VGPR -> fully register-resident.
__global__ __launch_bounds__(256, 2) void lut_fused(
    const float* __restrict__ x,
    const float* __restrict__ lut,
    const int*   __restrict__ mapping,
    float*       __restrict__ out)
{
    __shared__ __align__(16) float smem[OB * LROW];
    const int tid = threadIdx.x;
    const int o0  = blockIdx.x * OB;
    const int b0  = blockIdx.y * BB;
    const int o   = o0 + tid;

    // ---- stage lut tile (coalesced float4) into padded LDS ----
    const float4* lsrc = (const float4*)(lut + (size_t)o0 * NENT);
#pragma unroll
    for (int i = 0; i < (OB * NENT / 4) / 256; i++) {   // 16 iters
        const int f   = i * 256 + tid;                  // float4 index
        const float4 val = lsrc[f];
        const int ow  = f >> 4;                         // 16 float4 per row
        const int kw  = (f & 15) * 4;
        float* d = &smem[ow * LROW + kw];               // padded -> scalar stores
        d[0] = val.x; d[1] = val.y; d[2] = val.z; d[3] = val.w;
    }

    // mapping for my o (reused across all b of this block)
    int mp[NBITS];
#pragma unroll
    for (int j = 0; j < NBITS; j++) mp[j] = mapping[(size_t)o * NBITS + j];

    __syncthreads();

    // ---- pull my lut row (stride-65: bank (tid+k)%32, 2 lanes/bank = free) ----
    float v[NENT];
#pragma unroll
    for (int k = 0; k < NENT; k++) v[k] = smem[tid * LROW + k];

    // ---- in-register finite-difference transform: per bit j, hi -= lo ----
#pragma unroll
    for (int j = 0; j < NBITS; j++) {
#pragma unroll
        for (int k = 0; k < NENT; k++) {
            if ((k >> j) & 1) v[k] -= v[k ^ (1 << j)];
        }
    }

    __syncthreads();   // everyone done reading lut region before overwrite

    // ---- stage x tile (BB rows, coalesced float4 -> unpadded LDS) ----
    const float4* xsrc = (const float4*)(x + (size_t)b0 * IN_DIM);
    float4* xdst = (float4*)smem;
#pragma unroll
    for (int i = 0; i < (BB * IN_DIM / 4) / 256; i++) { // 16 iters
        const int f = i * 256 + tid;
        xdst[f] = xsrc[f];
    }
    __syncthreads();

    // ---- main loop: 6 LDS gathers + 63-FMA two-half Horner fold per output ----
    // Fold order: bits 0..4 within each 32-coeff half (peak 16 temps), bit 5
    // last via one combining FMA. Same FLOPs, half the live working set.
#pragma unroll 2
    for (int bi = 0; bi < BB; bi++) {
        float xv[NBITS];
#pragma unroll
        for (int j = 0; j < NBITS; j++) xv[j] = smem[bi * IN_DIM + mp[j]];

        float s0, s1;
        {
            float u[16];
#pragma unroll
            for (int m = 0; m < 16; m++)
                u[m] = fmaf(xv[0], v[2 * m + 1], v[2 * m]);
#pragma unroll
            for (int j = 1; j < 5; j++) {
#pragma unroll
                for (int m = 0; m < (16 >> j); m++)
                    u[m] = fmaf(xv[j], u[2 * m + 1], u[2 * m]);
            }
            s0 = u[0];
        }
        {
            float u[16];
#pragma unroll
            for (int m = 0; m < 16; m++)
                u[m] = fmaf(xv[0], v[32 + 2 * m + 1], v[32 + 2 * m]);
#pragma unroll
            for (int j = 1; j < 5; j++) {
#pragma unroll
                for (int m = 0; m < (16 >> j); m++)
                    u[m] = fmaf(xv[j], u[2 * m + 1], u[2 * m]);
            }
            s1 = u[0];
        }
        out[(size_t)(b0 + bi) * OUT_DIM + o] = fmaf(xv[5], s1, s0);
    }
}

extern "C" void kernel_launch(void* const* d_in, const int* in_sizes, int n_in,
                              void* d_out, int out_size, void* d_ws, size_t ws_size,
                              hipStream_t stream) {
    const float* x       = (const float*)d_in[0];
    const float* lut     = (const float*)d_in[1];
    const int*   mapping = (const int*)d_in[2];
    float*       out     = (float*)d_out;
    (void)d_ws; (void)ws_size;

    const dim3 grid(OUT_DIM / OB, B_DIM / BB);   // 8 x 64 = 512 blocks, 2/CU
    lut_fused<<<grid, 256, 0, stream>>>(x, lut, mapping, out);
}